// Round 6
// baseline (196.414 us; speedup 1.0000x reference)
//
#include <hip/hip_runtime.h>
#include <math.h>

typedef _Float16 half8 __attribute__((ext_vector_type(8)));
typedef __fp16 fp16x2 __attribute__((ext_vector_type(2)));
typedef float floatx16 __attribute__((ext_vector_type(16)));
typedef float float2v __attribute__((ext_vector_type(2)));

constexpr float L2E = 1.4426950408889634f;

// ---------------- constants ----------------
constexpr float DLO[8] = {-0.010597401784997278f, 0.032883011666982945f, 0.030841381835986965f,
                          -0.18703481171888114f, -0.02798376941698385f, 0.6308807679295904f,
                          0.7148465705525415f, 0.23037781330885523f};
constexpr float DHI[8] = {-0.23037781330885523f, 0.7148465705525415f, -0.6308807679295904f,
                          -0.02798376941698385f, 0.18703481171888114f, 0.030841381835986965f,
                          -0.032883011666982945f, -0.010597401784997278f};

constexpr float CT21[21] = {
  1.0f,          0.95557281f,  0.82623877f,  0.62348980f,  0.36534102f,  0.07473009f,
  -0.22252093f, -0.5f,        -0.73305187f, -0.90096887f, -0.98883083f,
  -0.98883083f, -0.90096887f, -0.73305187f, -0.5f,        -0.22252093f,
  0.07473009f,   0.36534102f,  0.62348980f,  0.82623877f,  0.95557281f};
constexpr float ST21[21] = {
  0.0f,          0.29475517f,  0.56332006f,  0.78183148f,  0.93087375f,  0.99720380f,
  0.97492791f,   0.86602540f,  0.68017274f,  0.43388374f,  0.14904227f,
  -0.14904227f, -0.43388374f, -0.68017274f, -0.86602540f, -0.97492791f,
  -0.99720380f, -0.93087375f, -0.78183148f, -0.56332006f, -0.29475517f};

template<int N>
__device__ __forceinline__ void dwt_step(const float* in, float* a, float* d) {
  constexpr int NO = (N + 7) / 2;
#pragma unroll
  for (int i = 0; i < NO; i++) {
    float sa = 0.f, sd = 0.f;
#pragma unroll
    for (int j = 0; j < 8; j++) {
      int rel = 2 * i + j - 6;
      int idx = (rel < 0) ? (-rel - 1) : ((rel >= N) ? (2 * N - rel - 1) : rel);
      float v = in[idx];
      sa = fmaf(v, DLO[7 - j], sa);
      sd = fmaf(v, DHI[7 - j], sd);
    }
    a[i] = sa;
    d[i] = sd;
  }
}

// direct HBM->LDS 16B staging (per-lane src affine in lane, dst = uniform+lane*16)
__device__ __forceinline__ void gload_lds16(const void* g, void* l) {
  __builtin_amdgcn_global_load_lds(
      (const __attribute__((address_space(1))) unsigned int*)g,
      (__attribute__((address_space(3))) unsigned int*)l, 16, 0, 0);
}

// compute the 88-wide feature row for one (b,s) into hrow (fp16)
__device__ __forceinline__ void feature_row(const float* __restrict__ xr,
                                            _Float16* hrow) {
  float xx[21];
#pragma unroll
  for (int t = 0; t < 21; t++) xx[t] = xr[t];

#pragma unroll
  for (int i = 78; i < 88; i++) hrow[i] = (_Float16)0.f;

#pragma unroll
  for (int t = 0; t < 21; t++) hrow[t] = (_Float16)xx[t];

#pragma unroll
  for (int k = 0; k < 11; k++) {
    float re = 0.f, im = 0.f;
#pragma unroll
    for (int t = 0; t < 21; t++) {
      const int m = (k * t) % 21;
      re = fmaf(xx[t], CT21[m], re);
      im = fmaf(xx[t], ST21[m], im);
    }
    hrow[21 + k] = (_Float16)sqrtf(re * re + im * im);
  }

  float a1[14], d1[14];
  dwt_step<21>(xx, a1, d1);
#pragma unroll
  for (int i = 0; i < 14; i++) hrow[64 + i] = (_Float16)d1[i];
  float a2[10], d2[10];
  dwt_step<14>(a1, a2, d2);
#pragma unroll
  for (int i = 0; i < 10; i++) hrow[54 + i] = (_Float16)d2[i];
  float a3[8], d3[8];
  dwt_step<10>(a2, a3, d3);
#pragma unroll
  for (int i = 0; i < 8; i++) hrow[46 + i] = (_Float16)d3[i];
  float a4[7], d4[7];
  dwt_step<8>(a3, a4, d4);
#pragma unroll
  for (int i = 0; i < 7; i++) {
    hrow[32 + i] = (_Float16)a4[i];
    hrow[39 + i] = (_Float16)d4[i];
  }
}

// ---------------- kernel 0: weight prep (R0 layout) ----------------
__global__ __launch_bounds__(256) void wprep_kernel(const float* __restrict__ cw,
                                                    const float* __restrict__ w_ih,
                                                    const float* __restrict__ b_ih,
                                                    const float* __restrict__ b_hh,
                                                    _Float16* __restrict__ WbT,
                                                    _Float16* __restrict__ wih16,
                                                    float* __restrict__ biasI) {
  int idx = blockIdx.x * 256 + threadIdx.x;
  if (idx < 64 * 264) {
    int o = idx / 264, k = idx - o * 264;
    float v = 0.f;
    if (k < 240) {
      int dk = k / 80, c = k - dk * 80;
      if (c < 78) v = cw[o * 234 + c * 3 + dk];
    }
    WbT[idx] = (_Float16)v;
  } else if (idx < 16896 + 8192) {
    int j = idx - 16896;
    wih16[j] = (_Float16)(L2E * w_ih[j]);
  } else if (idx < 16896 + 8192 + 128) {
    int g = idx - 16896 - 8192;
    int p = ((g & 63) << 1) | (g >> 6);
    biasI[p] = L2E * (b_ih[g] + b_hh[g]);
  }
}

// ---------------- LSTM helpers ----------------
__device__ __forceinline__ unsigned bcast_lane_u(unsigned v, int k) {
  return (unsigned)__builtin_amdgcn_readlane((int)v, k);
}

#if __has_builtin(__builtin_amdgcn_exp2f)
#define EXP2F __builtin_amdgcn_exp2f
#else
#define EXP2F exp2f
#endif

#if __has_builtin(__builtin_amdgcn_permlane32_swap)
__device__ __forceinline__ float swap_half(float x) {
  auto r = __builtin_amdgcn_permlane32_swap(__float_as_uint(x), __float_as_uint(x),
                                            false, false);
  return __uint_as_float(r[1]);
}
#else
__device__ __forceinline__ float swap_half(float x) { return __shfl_down(x, 32); }
#endif

// quad_perm [1,0,3,2]: swap with lane^1 (DPP, VALU pipe, no LDS)
__device__ __forceinline__ float dpp_swap1(float x) {
  int r = __builtin_amdgcn_update_dpp(0, __builtin_bit_cast(int, x),
                                      0xB1, 0xF, 0xF, true);
  return __builtin_bit_cast(float, r);
}

// v_cvt_pkrtz_f16_f32 {a,b} -> packed word (low = a)
__device__ __forceinline__ unsigned pkrtz_u(float a, float b) {
  auto h = __builtin_amdgcn_cvt_pkrtz(a, b);   // __fp16 ext_vector(2)
  return __builtin_bit_cast(unsigned, h);
}

// v_dot2_f32_f16: c += a.lo*b.lo + a.hi*b.hi
__device__ __forceinline__ float fdot2u(unsigned a, unsigned b, float c) {
#if __has_builtin(__builtin_amdgcn_fdot2)
  return __builtin_amdgcn_fdot2(__builtin_bit_cast(fp16x2, a),
                                __builtin_bit_cast(fp16x2, b), c, false);
#else
  fp16x2 av = __builtin_bit_cast(fp16x2, a);
  fp16x2 bv = __builtin_bit_cast(fp16x2, b);
  return c + (float)av[0] * (float)bv[0] + (float)av[1] * (float)bv[1];
#endif
}

// One LSTM step, dependency-hop-minimized (1 wave/SIMD => latency-bound).
// Lane L computes gates L and L+64. B-gate weights/x are PRE-SCALED by
// mArg (lo?2:-1) so gB is directly the exp2 argument. c is kept in
// K=2*log2e units so tanh(c) = 1-2*rcp(exp2(c)+1) with no scaling mul.
// sB = fma(mB,rB,aB) with per-lane constants covers both halves branchless.
// Matvec: 8 depth-2 dot2 chains per gate + 3-level add tree (5 hops).
__device__ __forceinline__ void lstm_step(float& h, float& c, float2v xg,
                                          const unsigned* __restrict__ wA2,
                                          const unsigned* __restrict__ wB2,
                                          float mArg, float mB, float aB) {
  unsigned q = pkrtz_u(h, dpp_swap1(h));   // even lane 2m: {h[2m],h[2m+1]}
  unsigned hp[16];
#pragma unroll
  for (int m = 0; m < 16; m++) hp[m] = bcast_lane_u(q, 2 * m);

  const float xb = xg.y * mArg;            // off critical path (xg loaded early)
  float A[8], B[8];
#pragma unroll
  for (int j = 0; j < 8; j++) {
    float a0 = (j == 0) ? xg.x : 0.f;
    float b0 = (j == 0) ? xb : 0.f;
    a0 = fdot2u(wA2[2 * j], hp[2 * j], a0);
    b0 = fdot2u(wB2[2 * j], hp[2 * j], b0);
    A[j] = fdot2u(wA2[2 * j + 1], hp[2 * j + 1], a0);
    B[j] = fdot2u(wB2[2 * j + 1], hp[2 * j + 1], b0);
  }
  float a01 = A[0] + A[1], a23 = A[2] + A[3], a45 = A[4] + A[5], a67 = A[6] + A[7];
  float b01 = B[0] + B[1], b23 = B[2] + B[3], b45 = B[4] + B[5], b67 = B[6] + B[7];
  float a03 = a01 + a23, a47 = a45 + a67;
  float b03 = b01 + b23, b47 = b45 + b67;
  const float gA = a03 + a47;              // log2e-scaled preact
  const float gB = b03 + b47;              // already the exp2 argument

  float rA = __builtin_amdgcn_rcpf(1.0f + EXP2F(-gA));   // sigmoid(A-gate)
  float rB = __builtin_amdgcn_rcpf(EXP2F(gB) + 1.0f);
  float sB = fmaf(mB, rB, aB);             // lo: K*tanh(g); hi: sigmoid(o)

  float fv = swap_half(rA);
  float ov = swap_half(sB);
  c = fmaf(fv, c, rA * sB);                // c in K units (lanes<32)
  float rc = __builtin_amdgcn_rcpf(EXP2F(c) + 1.0f);
  float ov2 = ov + ov;
  h = fmaf(-ov2, rc, ov);                  // h = ov * tanh(c_true)
}

// producer-wave barrier: 3 waves rendezvous on an LDS counter.
__device__ __forceinline__ void prod_barrier(int* pb, int& target) {
  target += 3;
  __builtin_amdgcn_s_waitcnt(0);
  if ((threadIdx.x & 63) == 0)
    __hip_atomic_fetch_add(pb, 1, __ATOMIC_RELEASE, __HIP_MEMORY_SCOPE_WORKGROUP);
  while (__hip_atomic_load(pb, __ATOMIC_ACQUIRE, __HIP_MEMORY_SCOPE_WORKGROUP) < target) {
  }
}

// ---------------- kernel 1: FUSED producer-consumer per batch ----------------
__global__ __launch_bounds__(256, 1)
__attribute__((amdgpu_waves_per_eu(1, 1)))
void fused_kernel(const float* __restrict__ x,
                  const _Float16* __restrict__ WbT,
                  const float* __restrict__ cbias,
                  const _Float16* __restrict__ wih16,
                  const float* __restrict__ biasI,
                  const float* __restrict__ w_hh,
                  const float* __restrict__ fc_w,
                  const float* __restrict__ fc_b,
                  float* __restrict__ Xp,
                  float* __restrict__ out) {
  __shared__ __align__(16) char smem[61184];
  __shared__ int ready;
  __shared__ int pbar;
  _Float16* At = (_Float16*)smem;
  _Float16* Bt = (_Float16*)(smem + 24576);
  _Float16* yt = (_Float16*)smem;
  _Float16* wl = (_Float16*)(smem + 9216);
  float* biasl = (float*)(smem + 27648);
  float* Xpt   = (float*)(smem + 28160);
  float* bl    = (float*)(smem + 60928);

  const int tid = threadIdx.x;
  const int b = blockIdx.x;

  if (tid == 0) { ready = 0; pbar = 0; }
  if (tid < 64) bl[tid] = cbias[tid];
  __syncthreads();   // ONLY full-block barrier; before wave specialization

  if (tid < 64) {
    // ================= consumer: LSTM + fc =================
    const int L = tid;
    const bool lo = (L < 32);
    const float K = 2.0f * L2E;
    const float mArg = lo ? 2.f : -1.f;
    const float mB = lo ? -2.f * K : 1.f;
    const float aB = lo ? K : 0.f;
    // packed fp16 weight pairs (k=2m,2m+1), log2e-prescaled; B also mArg-scaled
    unsigned wA2[16], wB2[16];
    {
      const float4* rAp = (const float4*)(w_hh + L * 32);
      const float4* rBp = (const float4*)(w_hh + (L + 64) * 32);
      const float sclB = L2E * mArg;
#pragma unroll
      for (int q = 0; q < 8; q++) {
        float4 a4 = rAp[q], b4 = rBp[q];
        wA2[2 * q]     = pkrtz_u(L2E * a4.x, L2E * a4.y);
        wA2[2 * q + 1] = pkrtz_u(L2E * a4.z, L2E * a4.w);
        wB2[2 * q]     = pkrtz_u(sclB * b4.x, sclB * b4.y);
        wB2[2 * q + 1] = pkrtz_u(sclB * b4.z, sclB * b4.w);
      }
    }

    float h = 0.f, c = 0.f;
    for (int k = 0; k < 8; k++) {
      while (__hip_atomic_load(&ready, __ATOMIC_ACQUIRE, __HIP_MEMORY_SCOPE_WORKGROUP) < k + 1)
        __builtin_amdgcn_s_sleep(2);
      const float* xp = Xp + ((size_t)b * 512 + (size_t)k * 64) * 128;
      float2v p2[4];
#pragma unroll
      for (int u = 0; u < 4; u++) p2[u] = *(const float2v*)&xp[u * 128 + 2 * L];
      for (int t0 = 0; t0 < 64; t0 += 4) {
        float2v c2[4];
#pragma unroll
        for (int u = 0; u < 4; u++) c2[u] = p2[u];
        if (t0 + 4 < 64) {
#pragma unroll
          for (int u = 0; u < 4; u++)
            p2[u] = *(const float2v*)&xp[(t0 + 4 + u) * 128 + 2 * L];
        }
#pragma unroll
        for (int u = 0; u < 4; u++)
          lstm_step(h, c, c2[u], wA2, wB2, mArg, mB, aB);
      }
    }

    float v = lo ? h * fc_w[L & 31] : 0.f;
#pragma unroll
    for (int off = 32; off > 0; off >>= 1) v += __shfl_down(v, off);
    if (L == 0) out[b] = v + fc_b[0];
  } else {
    // ================= producers: 3 waves, 8 tiles =================
    const int ptid = tid - 64;            // 0..191
    const int pw = (tid >> 6) - 1;        // producer wave id 0..2
    const int lane = tid & 63, ml = lane & 31, kg = lane >> 5;
    int bt = 0;                           // prod_barrier target

    for (int k = 0; k < 8; k++) {
      const int s0 = k * 128;

      // ---- phase A: async Bt restage + features -> At ----
      {
        const char* srcB = (const char*)WbT;
#pragma unroll
        for (int j = 0; j < 11; j++) {    // 2112 = 11*192 exactly
          const int idx = j * 192 + ptid;
          gload_lds16(srcB + (size_t)idx * 16, (char*)Bt + (size_t)idx * 16);
        }
      }
      if (ptid < 130) {
        const int s = s0 - 1 + ptid;      // row j=ptid <-> s = s0-1+j
        __align__(16) _Float16 hrow[88];
        if (s < 0 || s > 1023) {
#pragma unroll
          for (int i = 0; i < 88; i++) hrow[i] = (_Float16)0.f;
        } else {
          feature_row(x + ((size_t)(b << 10) + s) * 21, hrow);
        }
        uint4* dst = (uint4*)&At[ptid * 88];
        const uint4* src = (const uint4*)hrow;
#pragma unroll
        for (int i = 0; i < 11; i++) dst[i] = src[i];
      }
      prod_barrier(&pbar, bt);

      // ---- phase B: conv MFMA, 8 (mt,nt) wave-tiles over 3 waves ----
      float pooled[3][8];
      {
        int cc = 0;
        for (int wt = pw; wt < 8; wt += 3, cc++) {
          const int mt = wt & 3, nt = wt >> 2;
          floatx16 acc = {};
#pragma unroll
          for (int ks = 0; ks < 15; ks++) {
            const int kb = ks * 16 + kg * 8;
            const int dk = (kb >= 160) ? 2 : ((kb >= 80) ? 1 : 0);
            const int cofs = kb - dk * 80;
            half8 av = *(const half8*)&At[(mt * 32 + ml + dk) * 88 + cofs];
            half8 bv = *(const half8*)&Bt[(nt * 32 + ml) * 264 + kb];
            acc = __builtin_amdgcn_mfma_f32_32x32x16_f16(av, bv, acc, 0, 0, 0);
          }
          const float bo = bl[nt * 32 + ml];
#pragma unroll
          for (int p = 0; p < 8; p++)
            pooled[cc][p] = fmaxf(fmaxf(acc[2 * p], acc[2 * p + 1]) + bo, 0.f);
        }
      }
      prod_barrier(&pbar, bt);   // all conv reads of At/Bt done

      // ---- write yt (pooled fp16) + restage wl + biasl ----
      {
        int cc = 0;
        for (int wt = pw; wt < 8; wt += 3, cc++) {
          const int mt = wt & 3, nt = wt >> 2;
#pragma unroll
          for (int p = 0; p < 8; p++) {
            const int toff = (p & 1) + ((p >> 1) << 2);   // {0,1,4,5,8,9,12,13}
            const int t = mt * 16 + (kg << 1) + toff;
            yt[t * 72 + nt * 32 + ml] = (_Float16)pooled[cc][p];
          }
        }
        for (int i = ptid; i < 2048; i += 192) {
          int g = i >> 4, c4 = i & 15;
          *(uint2*)(wl + g * 72 + c4 * 4) = *(const uint2*)(wih16 + g * 64 + c4 * 4);
        }
        if (ptid < 128) biasl[ptid] = biasI[ptid];
      }
      prod_barrier(&pbar, bt);

      // ---- phase C: proj MFMA, 8 (pm,pn) tiles over 3 waves; scatter Xpt ----
      for (int wt = pw; wt < 8; wt += 3) {
        const int pm = wt & 1, pn = wt >> 1;
        floatx16 pa = {};
#pragma unroll
        for (int kq = 0; kq < 4; kq++) {
          const int k0 = kq * 16 + kg * 8;
          half8 av = *(const half8*)&yt[(pm * 32 + ml) * 72 + k0];
          half8 bv = *(const half8*)&wl[(pn * 32 + ml) * 72 + k0];
          pa = __builtin_amdgcn_mfma_f32_32x32x16_f16(av, bv, pa, 0, 0, 0);
        }
        const int gi = pn * 32 + ml;
        const int pp = ((gi & 63) << 1) | (gi >> 6);      // interleaved gate pos
#pragma unroll
        for (int reg = 0; reg < 16; reg++) {
          const int row = (reg & 3) + 8 * (reg >> 2) + 4 * kg;
          Xpt[(pm * 32 + row) * 128 + pp] = pa[reg];
        }
      }
      prod_barrier(&pbar, bt);

      // ---- coalesced Xp global writeout + bias ----
      {
        float* xpg = Xp + ((size_t)b * 512 + (size_t)k * 64) * 128;
        for (int i = ptid; i < 2048; i += 192) {
          const int r = i >> 5, c4 = (i & 31) << 2;
          float4 v = *(float4*)&Xpt[r * 128 + c4];
          float4 bb = *(float4*)&biasl[c4];
          v.x += bb.x; v.y += bb.y; v.z += bb.z; v.w += bb.w;
          *(float4*)&xpg[r * 128 + c4] = v;
        }
      }
      prod_barrier(&pbar, bt);   // all waves' Xp writes drained

      if (tid == 64)
        __hip_atomic_fetch_add(&ready, 1, __ATOMIC_RELEASE, __HIP_MEMORY_SCOPE_WORKGROUP);
    }
  }
}

// ---------------- launch ----------------
extern "C" void kernel_launch(void* const* d_in, const int* in_sizes, int n_in,
                              void* d_out, int out_size, void* d_ws, size_t ws_size,
                              hipStream_t stream) {
  const float* x      = (const float*)d_in[0];  // [256,1024,21]
  const float* conv_w = (const float*)d_in[1];  // [64,78,3]
  const float* conv_b = (const float*)d_in[2];  // [64]
  const float* w_ih   = (const float*)d_in[3];  // [128,64]
  const float* w_hh   = (const float*)d_in[4];  // [128,32]
  const float* b_ih   = (const float*)d_in[5];  // [128]
  const float* b_hh   = (const float*)d_in[6];  // [128]
  const float* fc_w   = (const float*)d_in[7];  // [1,32]
  const float* fc_b   = (const float*)d_in[8];  // [1]
  float* out = (float*)d_out;                   // [256,1]

  char* wsb = (char*)d_ws;
  // [Xp 67,108,864][WbT 33,792][wih16 16,384][biasI 512]
  float*    Xp    = (float*)wsb;
  _Float16* WbT   = (_Float16*)(wsb + 67108864);
  _Float16* wih16 = (_Float16*)(wsb + 67108864 + 33792);
  float*    biasI = (float*)(wsb + 67108864 + 33792 + 16384);

  wprep_kernel<<<dim3(99), dim3(256), 0, stream>>>(conv_w, w_ih, b_ih, b_hh,
                                                   WbT, wih16, biasI);
  fused_kernel<<<dim3(256), dim3(256), 0, stream>>>(x, WbT, conv_b, wih16, biasI,
                                                    w_hh, fc_w, fc_b, Xp, out);
}

// Round 7
// 183.377 us; speedup vs baseline: 1.0711x; 1.0711x over previous
//
#include <hip/hip_runtime.h>
#include <math.h>

typedef _Float16 half8 __attribute__((ext_vector_type(8)));
typedef __fp16 fp16x2 __attribute__((ext_vector_type(2)));
typedef float floatx16 __attribute__((ext_vector_type(16)));
typedef float float2v __attribute__((ext_vector_type(2)));

constexpr float L2E = 1.4426950408889634f;

// ---------------- constants ----------------
constexpr float DLO[8] = {-0.010597401784997278f, 0.032883011666982945f, 0.030841381835986965f,
                          -0.18703481171888114f, -0.02798376941698385f, 0.6308807679295904f,
                          0.7148465705525415f, 0.23037781330885523f};
constexpr float DHI[8] = {-0.23037781330885523f, 0.7148465705525415f, -0.6308807679295904f,
                          -0.02798376941698385f, 0.18703481171888114f, 0.030841381835986965f,
                          -0.032883011666982945f, -0.010597401784997278f};

constexpr float CT21[21] = {
  1.0f,          0.95557281f,  0.82623877f,  0.62348980f,  0.36534102f,  0.07473009f,
  -0.22252093f, -0.5f,        -0.73305187f, -0.90096887f, -0.98883083f,
  -0.98883083f, -0.90096887f, -0.73305187f, -0.5f,        -0.22252093f,
  0.07473009f,   0.36534102f,  0.62348980f,  0.82623877f,  0.95557281f};
constexpr float ST21[21] = {
  0.0f,          0.29475517f,  0.56332006f,  0.78183148f,  0.93087375f,  0.99720380f,
  0.97492791f,   0.86602540f,  0.68017274f,  0.43388374f,  0.14904227f,
  -0.14904227f, -0.43388374f, -0.68017274f, -0.86602540f, -0.97492791f,
  -0.99720380f, -0.93087375f, -0.78183148f, -0.56332006f, -0.29475517f};

template<int N>
__device__ __forceinline__ void dwt_step(const float* in, float* a, float* d) {
  constexpr int NO = (N + 7) / 2;
#pragma unroll
  for (int i = 0; i < NO; i++) {
    float sa = 0.f, sd = 0.f;
#pragma unroll
    for (int j = 0; j < 8; j++) {
      int rel = 2 * i + j - 6;
      int idx = (rel < 0) ? (-rel - 1) : ((rel >= N) ? (2 * N - rel - 1) : rel);
      float v = in[idx];
      sa = fmaf(v, DLO[7 - j], sa);
      sd = fmaf(v, DHI[7 - j], sd);
    }
    a[i] = sa;
    d[i] = sd;
  }
}

// direct HBM->LDS 16B staging (per-lane src affine in lane, dst = uniform+lane*16)
__device__ __forceinline__ void gload_lds16(const void* g, void* l) {
  __builtin_amdgcn_global_load_lds(
      (const __attribute__((address_space(1))) unsigned int*)g,
      (__attribute__((address_space(3))) unsigned int*)l, 16, 0, 0);
}

// compute the 88-wide feature row for one (b,s) into hrow (fp16)
__device__ __forceinline__ void feature_row(const float* __restrict__ xr,
                                            _Float16* hrow) {
  float xx[21];
#pragma unroll
  for (int t = 0; t < 21; t++) xx[t] = xr[t];

#pragma unroll
  for (int i = 78; i < 88; i++) hrow[i] = (_Float16)0.f;

#pragma unroll
  for (int t = 0; t < 21; t++) hrow[t] = (_Float16)xx[t];

#pragma unroll
  for (int k = 0; k < 11; k++) {
    float re = 0.f, im = 0.f;
#pragma unroll
    for (int t = 0; t < 21; t++) {
      const int m = (k * t) % 21;
      re = fmaf(xx[t], CT21[m], re);
      im = fmaf(xx[t], ST21[m], im);
    }
    hrow[21 + k] = (_Float16)sqrtf(re * re + im * im);
  }

  float a1[14], d1[14];
  dwt_step<21>(xx, a1, d1);
#pragma unroll
  for (int i = 0; i < 14; i++) hrow[64 + i] = (_Float16)d1[i];
  float a2[10], d2[10];
  dwt_step<14>(a1, a2, d2);
#pragma unroll
  for (int i = 0; i < 10; i++) hrow[54 + i] = (_Float16)d2[i];
  float a3[8], d3[8];
  dwt_step<10>(a2, a3, d3);
#pragma unroll
  for (int i = 0; i < 8; i++) hrow[46 + i] = (_Float16)d3[i];
  float a4[7], d4[7];
  dwt_step<8>(a3, a4, d4);
#pragma unroll
  for (int i = 0; i < 7; i++) {
    hrow[32 + i] = (_Float16)a4[i];
    hrow[39 + i] = (_Float16)d4[i];
  }
}

// ---------------- kernel 0: weight prep ----------------
// biasI is gate-permuted AND pre-scaled by the B-gate fold s(g):
// s = 1 for i/f gates (A half), 2 for g gates, -1 for o gates, so the
// consumer's exp2 argument needs no per-step scaling.
__global__ __launch_bounds__(256) void wprep_kernel(const float* __restrict__ cw,
                                                    const float* __restrict__ w_ih,
                                                    const float* __restrict__ b_ih,
                                                    const float* __restrict__ b_hh,
                                                    _Float16* __restrict__ WbT,
                                                    _Float16* __restrict__ wih16,
                                                    float* __restrict__ biasI) {
  int idx = blockIdx.x * 256 + threadIdx.x;
  if (idx < 64 * 264) {
    int o = idx / 264, k = idx - o * 264;
    float v = 0.f;
    if (k < 240) {
      int dk = k / 80, c = k - dk * 80;
      if (c < 78) v = cw[o * 234 + c * 3 + dk];
    }
    WbT[idx] = (_Float16)v;
  } else if (idx < 16896 + 8192) {
    int j = idx - 16896;
    wih16[j] = (_Float16)(L2E * w_ih[j]);
  } else if (idx < 16896 + 8192 + 128) {
    int g = idx - 16896 - 8192;
    int p = ((g & 63) << 1) | (g >> 6);
    float s = (g < 64) ? 1.f : ((g < 96) ? 2.f : -1.f);
    biasI[p] = s * L2E * (b_ih[g] + b_hh[g]);
  }
}

// ---------------- LSTM helpers ----------------
__device__ __forceinline__ unsigned bcast_lane_u(unsigned v, int k) {
  return (unsigned)__builtin_amdgcn_readlane((int)v, k);
}

#if __has_builtin(__builtin_amdgcn_exp2f)
#define EXP2F __builtin_amdgcn_exp2f
#else
#define EXP2F exp2f
#endif

#if __has_builtin(__builtin_amdgcn_permlane32_swap)
__device__ __forceinline__ float swap_half(float x) {
  auto r = __builtin_amdgcn_permlane32_swap(__float_as_uint(x), __float_as_uint(x),
                                            false, false);
  return __uint_as_float(r[1]);
}
#else
__device__ __forceinline__ float swap_half(float x) { return __shfl_down(x, 32); }
#endif

// quad_perm [1,0,3,2]: swap with lane^1 (DPP, VALU pipe, no LDS)
__device__ __forceinline__ float dpp_swap1(float x) {
  int r = __builtin_amdgcn_update_dpp(0, __builtin_bit_cast(int, x),
                                      0xB1, 0xF, 0xF, true);
  return __builtin_bit_cast(float, r);
}

// v_cvt_pkrtz_f16_f32 {a,b} -> packed word (low = a)
__device__ __forceinline__ unsigned pkrtz_u(float a, float b) {
  auto h = __builtin_amdgcn_cvt_pkrtz(a, b);   // __fp16 ext_vector(2)
  return __builtin_bit_cast(unsigned, h);
}

// v_dot2_f32_f16: c += a.lo*b.lo + a.hi*b.hi
__device__ __forceinline__ float fdot2u(unsigned a, unsigned b, float c) {
#if __has_builtin(__builtin_amdgcn_fdot2)
  return __builtin_amdgcn_fdot2(__builtin_bit_cast(fp16x2, a),
                                __builtin_bit_cast(fp16x2, b), c, false);
#else
  fp16x2 av = __builtin_bit_cast(fp16x2, a);
  fp16x2 bv = __builtin_bit_cast(fp16x2, b);
  return c + (float)av[0] * (float)bv[0] + (float)av[1] * (float)bv[1];
#endif
}

// One LSTM step (R5 structure: 4 interleaved depth-8 dot2 chains, minimal
// instruction count). Lane L computes gates L and L+64. The B-gate path is
// PRE-SCALED (weights at init, x at producer writeout) by mArg=lo?2:-1 so
// gB is directly the exp2 argument; c is kept in K=2*log2e units so
// tanh(c_true) = 1-2*rcp(exp2(c)+1) with no scaling mul.
// sB = fma(mB,rB,aB) with per-lane constants covers both halves branchless.
__device__ __forceinline__ void lstm_step(float& h, float& c, float2v xg,
                                          const unsigned* __restrict__ wA2,
                                          const unsigned* __restrict__ wB2,
                                          float mB, float aB) {
  unsigned q = pkrtz_u(h, dpp_swap1(h));   // even lane 2m: {h[2m],h[2m+1]}
  unsigned hp[16];
#pragma unroll
  for (int m = 0; m < 16; m++) hp[m] = bcast_lane_u(q, 2 * m);

  float aA0 = xg.x, aA1 = 0.f, aB0 = xg.y, aB1 = 0.f;
#pragma unroll
  for (int m = 0; m < 8; m++) {
    aA0 = fdot2u(wA2[m], hp[m], aA0);
    aB0 = fdot2u(wB2[m], hp[m], aB0);
    aA1 = fdot2u(wA2[m + 8], hp[m + 8], aA1);
    aB1 = fdot2u(wB2[m + 8], hp[m + 8], aB1);
  }
  const float gA = aA0 + aA1;              // log2e-scaled preact
  const float gB = aB0 + aB1;              // already the exp2 argument

  float rA = __builtin_amdgcn_rcpf(1.0f + EXP2F(-gA));   // sigmoid(A-gate)
  float rB = __builtin_amdgcn_rcpf(EXP2F(gB) + 1.0f);
  float sB = fmaf(mB, rB, aB);             // lo: K*tanh(g); hi: sigmoid(o)

  float fv = swap_half(rA);
  float ov = swap_half(sB);
  c = fmaf(fv, c, rA * sB);                // c in K units (lanes<32)
  float rc = __builtin_amdgcn_rcpf(EXP2F(c) + 1.0f);
  float ov2 = ov + ov;
  h = fmaf(-ov2, rc, ov);                  // h = ov * tanh(c_true)
}

// producer-wave barrier: 3 waves rendezvous on an LDS counter.
__device__ __forceinline__ void prod_barrier(int* pb, int& target) {
  target += 3;
  __builtin_amdgcn_s_waitcnt(0);
  if ((threadIdx.x & 63) == 0)
    __hip_atomic_fetch_add(pb, 1, __ATOMIC_RELEASE, __HIP_MEMORY_SCOPE_WORKGROUP);
  while (__hip_atomic_load(pb, __ATOMIC_ACQUIRE, __HIP_MEMORY_SCOPE_WORKGROUP) < target) {
  }
}

// ---------------- kernel 1: FUSED producer-consumer per batch ----------------
__global__ __launch_bounds__(256, 1)
__attribute__((amdgpu_waves_per_eu(1, 1)))
void fused_kernel(const float* __restrict__ x,
                  const _Float16* __restrict__ WbT,
                  const float* __restrict__ cbias,
                  const _Float16* __restrict__ wih16,
                  const float* __restrict__ biasI,
                  const float* __restrict__ w_hh,
                  const float* __restrict__ fc_w,
                  const float* __restrict__ fc_b,
                  float* __restrict__ Xp,
                  float* __restrict__ out) {
  __shared__ __align__(16) char smem[61184];
  __shared__ int ready;
  __shared__ int pbar;
  _Float16* At = (_Float16*)smem;
  _Float16* Bt = (_Float16*)(smem + 24576);
  _Float16* yt = (_Float16*)smem;
  _Float16* wl = (_Float16*)(smem + 9216);
  float* biasl = (float*)(smem + 27648);
  float* Xpt   = (float*)(smem + 28160);
  float* bl    = (float*)(smem + 60928);

  const int tid = threadIdx.x;
  const int b = blockIdx.x;

  if (tid == 0) { ready = 0; pbar = 0; }
  if (tid < 64) bl[tid] = cbias[tid];
  __syncthreads();   // ONLY full-block barrier; before wave specialization

  if (tid < 64) {
    // ================= consumer: LSTM + fc =================
    const int L = tid;
    const bool lo = (L < 32);
    const float K = 2.0f * L2E;
    const float mB = lo ? -2.f * K : 1.f;
    const float aB = lo ? K : 0.f;
    const float sclB = L2E * (lo ? 2.f : -1.f);
    // packed fp16 weight pairs (k=2m,2m+1), log2e-prescaled; B also fold-scaled
    unsigned wA2[16], wB2[16];
    {
      const float4* rAp = (const float4*)(w_hh + L * 32);
      const float4* rBp = (const float4*)(w_hh + (L + 64) * 32);
#pragma unroll
      for (int q = 0; q < 8; q++) {
        float4 a4 = rAp[q], b4 = rBp[q];
        wA2[2 * q]     = pkrtz_u(L2E * a4.x, L2E * a4.y);
        wA2[2 * q + 1] = pkrtz_u(L2E * a4.z, L2E * a4.w);
        wB2[2 * q]     = pkrtz_u(sclB * b4.x, sclB * b4.y);
        wB2[2 * q + 1] = pkrtz_u(sclB * b4.z, sclB * b4.w);
      }
    }

    float h = 0.f, c = 0.f;
    for (int k = 0; k < 8; k++) {
      while (__hip_atomic_load(&ready, __ATOMIC_ACQUIRE, __HIP_MEMORY_SCOPE_WORKGROUP) < k + 1)
        __builtin_amdgcn_s_sleep(2);
      const float* xp = Xp + ((size_t)b * 512 + (size_t)k * 64) * 128;
      float2v p2[4];
#pragma unroll
      for (int u = 0; u < 4; u++) p2[u] = *(const float2v*)&xp[u * 128 + 2 * L];
      for (int t0 = 0; t0 < 64; t0 += 4) {
        float2v c2[4];
#pragma unroll
        for (int u = 0; u < 4; u++) c2[u] = p2[u];
        if (t0 + 4 < 64) {
#pragma unroll
          for (int u = 0; u < 4; u++)
            p2[u] = *(const float2v*)&xp[(t0 + 4 + u) * 128 + 2 * L];
        }
#pragma unroll
        for (int u = 0; u < 4; u++)
          lstm_step(h, c, c2[u], wA2, wB2, mB, aB);
      }
    }

    float v = lo ? h * fc_w[L & 31] : 0.f;
#pragma unroll
    for (int off = 32; off > 0; off >>= 1) v += __shfl_down(v, off);
    if (L == 0) out[b] = v + fc_b[0];
  } else {
    // ================= producers: 3 waves, 8 tiles =================
    const int ptid = tid - 64;            // 0..191
    const int pw = (tid >> 6) - 1;        // producer wave id 0..2
    const int lane = tid & 63, ml = lane & 31, kg = lane >> 5;
    int bt = 0;                           // prod_barrier target

    for (int k = 0; k < 8; k++) {
      const int s0 = k * 128;

      // ---- phase A: async Bt restage + features -> At ----
      {
        const char* srcB = (const char*)WbT;
#pragma unroll
        for (int j = 0; j < 11; j++) {    // 2112 = 11*192 exactly
          const int idx = j * 192 + ptid;
          gload_lds16(srcB + (size_t)idx * 16, (char*)Bt + (size_t)idx * 16);
        }
      }
      if (ptid < 130) {
        const int s = s0 - 1 + ptid;      // row j=ptid <-> s = s0-1+j
        __align__(16) _Float16 hrow[88];
        if (s < 0 || s > 1023) {
#pragma unroll
          for (int i = 0; i < 88; i++) hrow[i] = (_Float16)0.f;
        } else {
          feature_row(x + ((size_t)(b << 10) + s) * 21, hrow);
        }
        uint4* dst = (uint4*)&At[ptid * 88];
        const uint4* src = (const uint4*)hrow;
#pragma unroll
        for (int i = 0; i < 11; i++) dst[i] = src[i];
      }
      prod_barrier(&pbar, bt);

      // ---- phase B: conv MFMA, 8 (mt,nt) wave-tiles over 3 waves ----
      float pooled[3][8];
      {
        int cc = 0;
        for (int wt = pw; wt < 8; wt += 3, cc++) {
          const int mt = wt & 3, nt = wt >> 2;
          floatx16 acc = {};
#pragma unroll
          for (int ks = 0; ks < 15; ks++) {
            const int kb = ks * 16 + kg * 8;
            const int dk = (kb >= 160) ? 2 : ((kb >= 80) ? 1 : 0);
            const int cofs = kb - dk * 80;
            half8 av = *(const half8*)&At[(mt * 32 + ml + dk) * 88 + cofs];
            half8 bv = *(const half8*)&Bt[(nt * 32 + ml) * 264 + kb];
            acc = __builtin_amdgcn_mfma_f32_32x32x16_f16(av, bv, acc, 0, 0, 0);
          }
          const float bo = bl[nt * 32 + ml];
#pragma unroll
          for (int p = 0; p < 8; p++)
            pooled[cc][p] = fmaxf(fmaxf(acc[2 * p], acc[2 * p + 1]) + bo, 0.f);
        }
      }
      prod_barrier(&pbar, bt);   // all conv reads of At/Bt done

      // ---- write yt (pooled fp16) + restage wl + biasl ----
      {
        int cc = 0;
        for (int wt = pw; wt < 8; wt += 3, cc++) {
          const int mt = wt & 3, nt = wt >> 2;
#pragma unroll
          for (int p = 0; p < 8; p++) {
            const int toff = (p & 1) + ((p >> 1) << 2);   // {0,1,4,5,8,9,12,13}
            const int t = mt * 16 + (kg << 1) + toff;
            yt[t * 72 + nt * 32 + ml] = (_Float16)pooled[cc][p];
          }
        }
        for (int i = ptid; i < 2048; i += 192) {
          int g = i >> 4, c4 = i & 15;
          *(uint2*)(wl + g * 72 + c4 * 4) = *(const uint2*)(wih16 + g * 64 + c4 * 4);
        }
        if (ptid < 128) biasl[ptid] = biasI[ptid];
      }
      prod_barrier(&pbar, bt);

      // ---- phase C: proj MFMA, 8 (pm,pn) tiles over 3 waves; scatter Xpt ----
      for (int wt = pw; wt < 8; wt += 3) {
        const int pm = wt & 1, pn = wt >> 1;
        floatx16 pa = {};
#pragma unroll
        for (int kq = 0; kq < 4; kq++) {
          const int k0 = kq * 16 + kg * 8;
          half8 av = *(const half8*)&yt[(pm * 32 + ml) * 72 + k0];
          half8 bv = *(const half8*)&wl[(pn * 32 + ml) * 72 + k0];
          pa = __builtin_amdgcn_mfma_f32_32x32x16_f16(av, bv, pa, 0, 0, 0);
        }
        const int gi = pn * 32 + ml;
        const int pp = ((gi & 63) << 1) | (gi >> 6);      // interleaved gate pos
#pragma unroll
        for (int reg = 0; reg < 16; reg++) {
          const int row = (reg & 3) + 8 * (reg >> 2) + 4 * kg;
          Xpt[(pm * 32 + row) * 128 + pp] = pa[reg];
        }
      }
      prod_barrier(&pbar, bt);

      // ---- coalesced Xp global writeout + bias + B-col fold scale ----
      {
        float* xpg = Xp + ((size_t)b * 512 + (size_t)k * 64) * 128;
        for (int i = ptid; i < 2048; i += 192) {
          const int r = i >> 5, c4 = (i & 31) << 2;
          const float sOdd = (c4 < 64) ? 2.f : -1.f;  // odd cols = B gates
          float4 v = *(float4*)&Xpt[r * 128 + c4];
          float4 bb = *(float4*)&biasl[c4];           // biasI pre-scaled
          v.x += bb.x; v.y = fmaf(v.y, sOdd, bb.y);
          v.z += bb.z; v.w = fmaf(v.w, sOdd, bb.w);
          *(float4*)&xpg[r * 128 + c4] = v;
        }
      }
      prod_barrier(&pbar, bt);   // all waves' Xp writes drained

      if (tid == 64)
        __hip_atomic_fetch_add(&ready, 1, __ATOMIC_RELEASE, __HIP_MEMORY_SCOPE_WORKGROUP);
    }
  }
}

// ---------------- launch ----------------
extern "C" void kernel_launch(void* const* d_in, const int* in_sizes, int n_in,
                              void* d_out, int out_size, void* d_ws, size_t ws_size,
                              hipStream_t stream) {
  const float* x      = (const float*)d_in[0];  // [256,1024,21]
  const float* conv_w = (const float*)d_in[1];  // [64,78,3]
  const float* conv_b = (const float*)d_in[2];  // [64]
  const float* w_ih   = (const float*)d_in[3];  // [128,64]
  const float* w_hh   = (const float*)d_in[4];  // [128,32]
  const float* b_ih   = (const float*)d_in[5];  // [128]
  const float* b_hh   = (const float*)d_in[6];  // [128]
  const float* fc_w   = (const float*)d_in[7];  // [1,32]
  const float* fc_b   = (const float*)d_in[8];  // [1]
  float* out = (float*)d_out;                   // [256,1]

  char* wsb = (char*)d_ws;
  // [Xp 67,108,864][WbT 33,792][wih16 16,384][biasI 512]
  float*    Xp    = (float*)wsb;
  _Float16* WbT   = (_Float16*)(wsb + 67108864);
  _Float16* wih16 = (_Float16*)(wsb + 67108864 + 33792);
  float*    biasI = (float*)(wsb + 67108864 + 33792 + 16384);

  wprep_kernel<<<dim3(99), dim3(256), 0, stream>>>(conv_w, w_ih, b_ih, b_hh,
                                                   WbT, wih16, biasI);
  fused_kernel<<<dim3(256), dim3(256), 0, stream>>>(x, WbT, conv_b, wih16, biasI,
                                                    w_hh, fc_w, fc_b, Xp, out);
}